// Round 7
// baseline (127.278 us; speedup 1.0000x reference)
//
#include <hip/hip_runtime.h>
#include <cstddef>

#define BB  32
#define CC  128
#define HH  64
#define WW  64
#define OO  256
#define OHH 32
#define OWW 32
#define YSTR 196   // yr row stride (bf16): 392B -> 2-way banks (free)
#define PSTR 296   // patchT row stride: 288 data + 8 pad; 592B rows, 16B-aligned

typedef __bf16 bf16x8 __attribute__((ext_vector_type(8)));
typedef __bf16 bf16x4 __attribute__((ext_vector_type(4)));
typedef float  f32x4  __attribute__((ext_vector_type(4)));

// ---- weight transform: w[o][c][3][3] f32 -> wt[o][k][c] bf16 (k = kh*3+kw) ----
__global__ void wtrans_bf16_kernel(const float* __restrict__ w, __bf16* __restrict__ wt) {
    int idx = blockIdx.x * 256 + threadIdx.x;          // (o*9 + k)*128 + c
    if (idx >= OO * 9 * CC) return;
    int c    = idx & 127;
    int rest = idx >> 7;
    int k    = rest % 9;
    int o    = rest / 9;
    wt[idx] = (__bf16)w[((size_t)o * CC + c) * 9 + k];
}

// ---- fused bilinear-im2col + bf16 MFMA; grid (b=32, p=32), 256 thr = 4 waves ----
__global__ __launch_bounds__(256, 5)
void conv_mfma_kernel(const float* __restrict__ x, const __bf16* __restrict__ wt,
                      const float* __restrict__ bias, const float* __restrict__ shp,
                      const float* __restrict__ swp, float* __restrict__ out) {
    __shared__ __bf16 yr[32 * YSTR];       // 12544 B  row-interp [c][kh][w]
    __shared__ __bf16 patchT[32 * PSTR];   // 18944 B  B-operand [q][k*32+c]

    const int tid = threadIdx.x;
    const int b   = blockIdx.x;
    const int p   = blockIdx.y;
    const float sh = shp[0];
    const float sw = swp[0];

    const float hpos = (float)p * sh - 1.0f;
    const float hbf  = floorf(hpos);
    const float fh   = hpos - hbf;
    const int   hb   = (int)hbf;

    // ---- bias-only fast path (all sampled rows OOB) ----
    if (hb >= HH || hb <= -4) {
#pragma unroll
        for (int rep = 0; rep < 8; ++rep) {
            int o  = rep * 32 + (tid >> 3);
            int q0 = (tid & 7) << 2;
            float bv = bias[o];
            float4 r; r.x = bv; r.y = bv; r.z = bv; r.w = bv;
            *(float4*)(out + (((size_t)b * OO + o) * OHH + p) * OWW + q0) = r;
        }
        return;
    }

    const int wv = tid >> 6;     // wave -> o block
    const int l  = tid & 63;
    const int lr = l & 15;
    const int lg = l >> 4;
    const int o0 = wv * 64;

    // x-load ownership
    const int cA   = tid >> 4;            // 0..15 (channel within chunk, +16 for i=1)
    const int col4 = (tid & 15) << 2;     // 0..60

    int  hr[4];
    bool rvb[4];
#pragma unroll
    for (int r = 0; r < 4; ++r) {
        hr[r]  = hb + r;
        rvb[r] = (hr[r] >= 0) && (hr[r] < HH);
    }

    // stage-B ownership: c = tid&31, q in {q0, q0+8, q0+16, q0+24}
    const int cB = tid & 31;
    const int q0 = tid >> 5;
    float fwr[4];
    int   wbr[4];
#pragma unroll
    for (int j = 0; j < 4; ++j) {
        float wpos = (float)(q0 + 8 * j) * sw - 1.0f;
        float wbf  = floorf(wpos);
        fwr[j] = wpos - wbf;
        wbr[j] = (int)wbf;
    }

    f32x4 acc[4][2];
#pragma unroll
    for (int ot = 0; ot < 4; ++ot)
#pragma unroll
        for (int qt = 0; qt < 2; ++qt) acc[ot][qt] = (f32x4)0.0f;

    // de-convoy: co-resident blocks are {same b, p += 8} -> use p>>3 so each
    // of the 4 co-resident blocks starts on a DIFFERENT c-chunk/phase.
    const int phase = ((p >> 3) + b) & 3;

    // prefetch + row-interp first chunk into bf16 regs
    bf16x4 y[2][3];
    {
        const int c0p = phase * 32;
#pragma unroll
        for (int i = 0; i < 2; ++i) {
            const float* xp = x + ((size_t)(b * CC + c0p + cA + i * 16) * HH) * WW + col4;
            float4 v[4];
#pragma unroll
            for (int r = 0; r < 4; ++r) {
                float4 t = {0.f, 0.f, 0.f, 0.f};
                if (rvb[r]) t = *(const float4*)(xp + (size_t)hr[r] * WW);
                v[r] = t;
            }
#pragma unroll
            for (int kh = 0; kh < 3; ++kh) {
                bf16x4 t;
                t[0] = (__bf16)(v[kh].x + fh * (v[kh + 1].x - v[kh].x));
                t[1] = (__bf16)(v[kh].y + fh * (v[kh + 1].y - v[kh].y));
                t[2] = (__bf16)(v[kh].z + fh * (v[kh + 1].z - v[kh].z));
                t[3] = (__bf16)(v[kh].w + fh * (v[kh + 1].w - v[kh].w));
                y[i][kh] = t;
            }
        }
    }

    for (int cc = 0; cc < 4; ++cc) {
        const int chunk = (cc + phase) & 3;
        const int c0 = chunk * 32;

        // ---- 1. yr write from interp regs ----
#pragma unroll
        for (int i = 0; i < 2; ++i)
#pragma unroll
            for (int kh = 0; kh < 3; ++kh)
                *(bf16x4*)&yr[(cA + i * 16) * YSTR + kh * 64 + col4] = y[i][kh];
        __syncthreads();   // barA: yr ready; prev MFMA's patchT reads drained

        // ---- 2. issue next-iteration x loads (latency spans stage B + MFMA) ----
        float4 xv[2][4];
        if (cc < 3) {
            const int c0n = ((cc + 1 + phase) & 3) * 32;
#pragma unroll
            for (int i = 0; i < 2; ++i) {
                const float* xp = x + ((size_t)(b * CC + c0n + cA + i * 16) * HH) * WW + col4;
#pragma unroll
                for (int r = 0; r < 4; ++r) {
                    float4 t = {0.f, 0.f, 0.f, 0.f};
                    if (rvb[r]) t = *(const float4*)(xp + (size_t)hr[r] * WW);
                    xv[i][r] = t;
                }
            }
        }

        // ---- 3. stage B: col interp yr -> patchT (4 reads serve 3 taps) ----
#pragma unroll
        for (int j = 0; j < 4; ++j) {
            const int   q   = q0 + 8 * j;
            const float fw  = fwr[j];
            const int   wb0 = wbr[j];
            __bf16* pq = &patchT[q * PSTR + cB];
#pragma unroll
            for (int kh = 0; kh < 3; ++kh) {
                const __bf16* yb = &yr[cB * YSTR + kh * 64];
                float s[4];
#pragma unroll
                for (int t = 0; t < 4; ++t) {
                    int w = wb0 + t;
                    s[t] = ((unsigned)w < WW) ? (float)yb[w] : 0.0f;
                }
#pragma unroll
                for (int kw = 0; kw < 3; ++kw)
                    pq[(kh * 3 + kw) * 32] = (__bf16)(s[kw] + fw * (s[kw + 1] - s[kw]));
            }
        }
        __syncthreads();   // barB: patchT ready; yr reads drained (NOT xv)

        // ---- 4. MFMA: 9 taps x (4o x 2q); A loaded in-loop (compiler pipelines) ----
        __builtin_amdgcn_s_setprio(1);
#pragma unroll
        for (int k = 0; k < 9; ++k) {
            const __bf16* wp = wt + ((size_t)(o0 + lr) * 9 + k) * CC + c0 + lg * 8;
            bf16x8 a0 = *(const bf16x8*)(wp + (size_t)0  * 9 * CC);
            bf16x8 a1 = *(const bf16x8*)(wp + (size_t)16 * 9 * CC);
            bf16x8 a2 = *(const bf16x8*)(wp + (size_t)32 * 9 * CC);
            bf16x8 a3 = *(const bf16x8*)(wp + (size_t)48 * 9 * CC);
            bf16x8 b0 = *(const bf16x8*)&patchT[lr * PSTR + k * 32 + lg * 8];
            bf16x8 b1 = *(const bf16x8*)&patchT[(16 + lr) * PSTR + k * 32 + lg * 8];
            acc[0][0] = __builtin_amdgcn_mfma_f32_16x16x32_bf16(a0, b0, acc[0][0], 0, 0, 0);
            acc[0][1] = __builtin_amdgcn_mfma_f32_16x16x32_bf16(a0, b1, acc[0][1], 0, 0, 0);
            acc[1][0] = __builtin_amdgcn_mfma_f32_16x16x32_bf16(a1, b0, acc[1][0], 0, 0, 0);
            acc[1][1] = __builtin_amdgcn_mfma_f32_16x16x32_bf16(a1, b1, acc[1][1], 0, 0, 0);
            acc[2][0] = __builtin_amdgcn_mfma_f32_16x16x32_bf16(a2, b0, acc[2][0], 0, 0, 0);
            acc[2][1] = __builtin_amdgcn_mfma_f32_16x16x32_bf16(a2, b1, acc[2][1], 0, 0, 0);
            acc[3][0] = __builtin_amdgcn_mfma_f32_16x16x32_bf16(a3, b0, acc[3][0], 0, 0, 0);
            acc[3][1] = __builtin_amdgcn_mfma_f32_16x16x32_bf16(a3, b1, acc[3][1], 0, 0, 0);
        }
        __builtin_amdgcn_s_setprio(0);

        // ---- 5. row-interp next chunk (xv vmcnt drain hid under stage B+MFMA) ----
        if (cc < 3) {
#pragma unroll
            for (int i = 0; i < 2; ++i)
#pragma unroll
                for (int kh = 0; kh < 3; ++kh) {
                    bf16x4 t;
                    t[0] = (__bf16)(xv[i][kh].x + fh * (xv[i][kh + 1].x - xv[i][kh].x));
                    t[1] = (__bf16)(xv[i][kh].y + fh * (xv[i][kh + 1].y - xv[i][kh].y));
                    t[2] = (__bf16)(xv[i][kh].z + fh * (xv[i][kh + 1].z - xv[i][kh].z));
                    t[3] = (__bf16)(xv[i][kh].w + fh * (xv[i][kh + 1].w - xv[i][kh].w));
                    y[i][kh] = t;
                }
        }
        // patchT overwrite fenced by next barA; yr overwrite fenced by barB.
    }

    // ---- epilogue: + bias, store (C/D: col=lane&15, row=(lane>>4)*4+reg) ----
#pragma unroll
    for (int ot = 0; ot < 4; ++ot) {
#pragma unroll
        for (int r = 0; r < 4; ++r) {
            int o = o0 + ot * 16 + lg * 4 + r;
            float bv = bias[o];
            float* op = out + (((size_t)b * OO + o) * OHH + p) * OWW;
            op[lr]      = acc[ot][0][r] + bv;
            op[16 + lr] = acc[ot][1][r] + bv;
        }
    }
}

// ---- fp32 fallback (no workspace) ----
__global__ __launch_bounds__(256)
void conv_fallback_kernel(const float* __restrict__ x, const float* __restrict__ w,
                          const float* __restrict__ bias, const float* __restrict__ shp,
                          const float* __restrict__ swp, float* __restrict__ out) {
    __shared__ __align__(16) float xr[4][WW];
    __shared__ __align__(16) float patch[9][OWW];
    const int tid = threadIdx.x;
    const int p = blockIdx.y;
    const int b = blockIdx.x;
    const float sh = shp[0];
    const float sw = swp[0];
    const float hpos = (float)p * sh - 1.0f;
    const float hbf  = floorf(hpos);
    const float fh   = hpos - hbf;
    const int   hb   = (int)hbf;
    const int og = tid & 63;
    const int qg = tid >> 6;
    const int o0 = og * 4;
    const int q0 = qg * 8;
    const int rr   = tid >> 6;
    const int colc = tid & 63;
    const int rowg = hb + rr;
    const bool rv = (rowg >= 0) && (rowg < HH);
    float acc[4][8];
#pragma unroll
    for (int i = 0; i < 4; ++i)
#pragma unroll
        for (int j = 0; j < 8; ++j) acc[i][j] = 0.0f;
    for (int c = 0; c < CC; ++c) {
        float vv = 0.0f;
        if (rv) vv = x[(((size_t)b * CC + c) * HH + rowg) * WW + colc];
        xr[rr][colc] = vv;
        __syncthreads();
        for (int it = tid; it < 9 * OWW; it += 256) {
            int k = it >> 5; int q = it & 31;
            int kh = k / 3;  int kw = k - kh * 3;
            float wpos = (float)q * sw - 1.0f + (float)kw;
            float wbf = floorf(wpos);
            float fw = wpos - wbf;
            int wb = (int)wbf;
            float x00 = 0, x01 = 0, x10 = 0, x11 = 0;
            if (wb >= 0 && wb < WW)         { x00 = xr[kh][wb];     x10 = xr[kh + 1][wb]; }
            if (wb + 1 >= 0 && wb + 1 < WW) { x01 = xr[kh][wb + 1]; x11 = xr[kh + 1][wb + 1]; }
            float top = x00 * (1.0f - fw) + x01 * fw;
            float bot = x10 * (1.0f - fw) + x11 * fw;
            patch[k][q] = top * (1.0f - fh) + bot * fh;
        }
        __syncthreads();
        const float4* pv = (const float4*)&patch[0][0];
#pragma unroll
        for (int k = 0; k < 9; ++k) {
            const float* wb_ = w + (size_t)o0 * (CC * 9) + c * 9 + k;
            float wvv[4] = {wb_[0], wb_[1 * CC * 9], wb_[2 * CC * 9], wb_[3 * CC * 9]};
            float4 pa = pv[k * 8 + (q0 >> 2)];
            float4 pb = pv[k * 8 + (q0 >> 2) + 1];
#pragma unroll
            for (int oo2 = 0; oo2 < 4; ++oo2) {
                acc[oo2][0] += wvv[oo2] * pa.x; acc[oo2][1] += wvv[oo2] * pa.y;
                acc[oo2][2] += wvv[oo2] * pa.z; acc[oo2][3] += wvv[oo2] * pa.w;
                acc[oo2][4] += wvv[oo2] * pb.x; acc[oo2][5] += wvv[oo2] * pb.y;
                acc[oo2][6] += wvv[oo2] * pb.z; acc[oo2][7] += wvv[oo2] * pb.w;
            }
        }
    }
    float4 bv = ((const float4*)bias)[og];
    float bvv[4] = {bv.x, bv.y, bv.z, bv.w};
#pragma unroll
    for (int oo2 = 0; oo2 < 4; ++oo2) {
        size_t off = (((size_t)b * OO + o0 + oo2) * OHH + p) * OWW + q0;
        float4 r0, r1;
        r0.x = acc[oo2][0] + bvv[oo2]; r0.y = acc[oo2][1] + bvv[oo2];
        r0.z = acc[oo2][2] + bvv[oo2]; r0.w = acc[oo2][3] + bvv[oo2];
        r1.x = acc[oo2][4] + bvv[oo2]; r1.y = acc[oo2][5] + bvv[oo2];
        r1.z = acc[oo2][6] + bvv[oo2]; r1.w = acc[oo2][7] + bvv[oo2];
        *(float4*)(out + off)     = r0;
        *(float4*)(out + off + 4) = r1;
    }
}

extern "C" void kernel_launch(void* const* d_in, const int* in_sizes, int n_in,
                              void* d_out, int out_size, void* d_ws, size_t ws_size,
                              hipStream_t stream) {
    const float* x    = (const float*)d_in[0];
    const float* w    = (const float*)d_in[1];
    const float* bias = (const float*)d_in[2];
    const float* shp  = (const float*)d_in[3];
    const float* swp  = (const float*)d_in[4];
    float* out = (float*)d_out;

    const size_t wt_bytes = (size_t)OO * 9 * CC * sizeof(__bf16);   // 576 KB
    dim3 grid(BB, OHH);
    if (ws_size >= wt_bytes) {
        __bf16* wtp = (__bf16*)d_ws;
        int n = OO * 9 * CC;
        wtrans_bf16_kernel<<<(n + 255) / 256, 256, 0, stream>>>(w, wtp);
        conv_mfma_kernel<<<grid, 256, 0, stream>>>(x, wtp, bias, shp, swp, out);
    } else {
        conv_fallback_kernel<<<grid, 256, 0, stream>>>(x, w, bias, shp, swp, out);
    }
}

// Round 8
// 84.460 us; speedup vs baseline: 1.5070x; 1.5070x over previous
//
#include <hip/hip_runtime.h>
#include <cstddef>

#define BB  32
#define CC  128
#define HH  64
#define WW  64
#define OO  256
#define OHH 32
#define OWW 32
#define YSTR 196   // yr row stride (bf16): 392B -> 2-way banks (free)
#define PSTR 296   // patchT row stride: 288 data + 8 pad; 592B rows, 16B-aligned

typedef __bf16 bf16x8 __attribute__((ext_vector_type(8)));
typedef __bf16 bf16x4 __attribute__((ext_vector_type(4)));
typedef __bf16 bf16x2 __attribute__((ext_vector_type(2)));
typedef float  f32x4  __attribute__((ext_vector_type(4)));

// ---- weight transform: w[o][c][3][3] f32 -> wt[o][k][c] bf16 (k = kh*3+kw) ----
__global__ void wtrans_bf16_kernel(const float* __restrict__ w, __bf16* __restrict__ wt) {
    int idx = blockIdx.x * 256 + threadIdx.x;          // (o*9 + k)*128 + c
    if (idx >= OO * 9 * CC) return;
    int c    = idx & 127;
    int rest = idx >> 7;
    int k    = rest % 9;
    int o    = rest / 9;
    wt[idx] = (__bf16)w[((size_t)o * CC + c) * 9 + k];
}

// ---- fused bilinear-im2col + bf16 MFMA; grid (b=32, p=32), 512 thr = 8 waves ----
// 4 blocks/CU x 8 waves = 32 waves/CU (100% theoretical occupancy).
// Each wave owns 32 o x 32 q -> acc[2][2] (16 VGPR).
__global__ __launch_bounds__(512, 8)
void conv_mfma_kernel(const float* __restrict__ x, const __bf16* __restrict__ wt,
                      const float* __restrict__ bias, const float* __restrict__ shp,
                      const float* __restrict__ swp, float* __restrict__ out) {
    __shared__ __bf16 yr[32 * YSTR];       // 12544 B  row-interp [c][kh][w]
    __shared__ __bf16 patchT[32 * PSTR];   // 18944 B  B-operand [q][k*32+c]

    const int tid = threadIdx.x;
    const int b   = blockIdx.x;
    const int p   = blockIdx.y;
    const float sh = shp[0];
    const float sw = swp[0];

    const float hpos = (float)p * sh - 1.0f;
    const float hbf  = floorf(hpos);
    const float fh   = hpos - hbf;
    const int   hb   = (int)hbf;

    // ---- bias-only fast path (all sampled rows OOB); 8192 f32 = 2048 float4 ----
    if (hb >= HH || hb <= -4) {
#pragma unroll
        for (int j = 0; j < 4; ++j) {
            int fi = j * 512 + tid;        // float4 index within (b,p) tile
            int o  = fi >> 3;              // 8 float4 per o-row (32 q)
            int qf = fi & 7;
            float bv = bias[o];
            float4 r; r.x = bv; r.y = bv; r.z = bv; r.w = bv;
            *(float4*)(out + (((size_t)b * OO + o) * OHH + p) * OWW + qf * 4) = r;
        }
        return;
    }

    const int wv = tid >> 6;     // wave id 0..7 -> o block of 32
    const int l  = tid & 63;
    const int lr = l & 15;
    const int lg = l >> 4;
    const int o0 = wv * 32;

    // stage-A ownership: c = tid>>4 (0..31), 4 consecutive cols
    const int cA   = tid >> 4;
    const int col4 = (tid & 15) << 2;

    int  hr[4];
    bool rvb[4];
#pragma unroll
    for (int r = 0; r < 4; ++r) {
        hr[r]  = hb + r;
        rvb[r] = (hr[r] >= 0) && (hr[r] < HH);
    }

    // stage-B ownership: one q (tid>>4), two consecutive c ((tid&15)*2)
    const int qB  = tid >> 4;            // 0..31
    const int cB0 = (tid & 15) * 2;      // 0..30 even
    const float wposB = (float)qB * sw - 1.0f;
    const float wbfB  = floorf(wposB);
    const float fw    = wposB - wbfB;
    const int   wb    = (int)wbfB;

    f32x4 acc[2][2];
#pragma unroll
    for (int ot = 0; ot < 2; ++ot)
#pragma unroll
        for (int qt = 0; qt < 2; ++qt) acc[ot][qt] = (f32x4)0.0f;

    for (int chunk = 0; chunk < 4; ++chunk) {
        const int c0 = chunk * 32;

        // ---- stage A: load x rows, row-interp, write yr ----
        {
            const float* xp = x + ((size_t)(b * CC + c0 + cA) * HH) * WW + col4;
            float4 v[4];
#pragma unroll
            for (int r = 0; r < 4; ++r) {
                float4 t = {0.f, 0.f, 0.f, 0.f};
                if (rvb[r]) t = *(const float4*)(xp + (size_t)hr[r] * WW);
                v[r] = t;
            }
            __bf16* yb = &yr[cA * YSTR + col4];
#pragma unroll
            for (int kh = 0; kh < 3; ++kh) {
                bf16x4 t;
                t[0] = (__bf16)(v[kh].x + fh * (v[kh + 1].x - v[kh].x));
                t[1] = (__bf16)(v[kh].y + fh * (v[kh + 1].y - v[kh].y));
                t[2] = (__bf16)(v[kh].z + fh * (v[kh + 1].z - v[kh].z));
                t[3] = (__bf16)(v[kh].w + fh * (v[kh + 1].w - v[kh].w));
                *(bf16x4*)(yb + kh * 64) = t;
            }
        }
        __syncthreads();   // barA: yr ready; prev chunk's patchT MFMA-reads drained

        // ---- stage B: col interp yr -> patchT; 4 reads serve 3 taps; paired-c b32 writes ----
        {
            __bf16* pq = &patchT[qB * PSTR + cB0];
#pragma unroll
            for (int kh = 0; kh < 3; ++kh) {
                const __bf16* yb0 = &yr[cB0 * YSTR + kh * 64];
                const __bf16* yb1 = &yr[(cB0 + 1) * YSTR + kh * 64];
                float s0[4], s1[4];
#pragma unroll
                for (int t = 0; t < 4; ++t) {
                    int w = wb + t;
                    bool valid = ((unsigned)w < WW);
                    s0[t] = valid ? (float)yb0[w] : 0.0f;
                    s1[t] = valid ? (float)yb1[w] : 0.0f;
                }
#pragma unroll
                for (int kw = 0; kw < 3; ++kw) {
                    bf16x2 pr;
                    pr[0] = (__bf16)(s0[kw] + fw * (s0[kw + 1] - s0[kw]));
                    pr[1] = (__bf16)(s1[kw] + fw * (s1[kw + 1] - s1[kw]));
                    *(bf16x2*)(pq + (kh * 3 + kw) * 32) = pr;
                }
            }
        }
        __syncthreads();   // barB: patchT ready; yr reads drained

        // ---- MFMA: 9 taps x (2o x 2q); A loaded in-loop (compiler pipelines) ----
        __builtin_amdgcn_s_setprio(1);
#pragma unroll
        for (int k = 0; k < 9; ++k) {
            const __bf16* wp = wt + ((size_t)(o0 + lr) * 9 + k) * CC + c0 + lg * 8;
            bf16x8 a0 = *(const bf16x8*)(wp);
            bf16x8 a1 = *(const bf16x8*)(wp + (size_t)16 * 9 * CC);
            bf16x8 b0 = *(const bf16x8*)&patchT[lr * PSTR + k * 32 + lg * 8];
            bf16x8 b1 = *(const bf16x8*)&patchT[(16 + lr) * PSTR + k * 32 + lg * 8];
            acc[0][0] = __builtin_amdgcn_mfma_f32_16x16x32_bf16(a0, b0, acc[0][0], 0, 0, 0);
            acc[0][1] = __builtin_amdgcn_mfma_f32_16x16x32_bf16(a0, b1, acc[0][1], 0, 0, 0);
            acc[1][0] = __builtin_amdgcn_mfma_f32_16x16x32_bf16(a1, b0, acc[1][0], 0, 0, 0);
            acc[1][1] = __builtin_amdgcn_mfma_f32_16x16x32_bf16(a1, b1, acc[1][1], 0, 0, 0);
        }
        __builtin_amdgcn_s_setprio(0);
        // patchT overwrite fenced by next barA; yr overwrite fenced by barB.
    }

    // ---- epilogue: + bias, store (C/D: col=lane&15, row=(lane>>4)*4+reg) ----
#pragma unroll
    for (int ot = 0; ot < 2; ++ot) {
#pragma unroll
        for (int r = 0; r < 4; ++r) {
            int o = o0 + ot * 16 + lg * 4 + r;
            float bv = bias[o];
            float* op = out + (((size_t)b * OO + o) * OHH + p) * OWW;
            op[lr]      = acc[ot][0][r] + bv;
            op[16 + lr] = acc[ot][1][r] + bv;
        }
    }
}

// ---- fp32 fallback (no workspace) ----
__global__ __launch_bounds__(256)
void conv_fallback_kernel(const float* __restrict__ x, const float* __restrict__ w,
                          const float* __restrict__ bias, const float* __restrict__ shp,
                          const float* __restrict__ swp, float* __restrict__ out) {
    __shared__ __align__(16) float xr[4][WW];
    __shared__ __align__(16) float patch[9][OWW];
    const int tid = threadIdx.x;
    const int p = blockIdx.y;
    const int b = blockIdx.x;
    const float sh = shp[0];
    const float sw = swp[0];
    const float hpos = (float)p * sh - 1.0f;
    const float hbf  = floorf(hpos);
    const float fh   = hpos - hbf;
    const int   hb   = (int)hbf;
    const int og = tid & 63;
    const int qg = tid >> 6;
    const int o0 = og * 4;
    const int q0 = qg * 8;
    const int rr   = tid >> 6;
    const int colc = tid & 63;
    const int rowg = hb + rr;
    const bool rv = (rowg >= 0) && (rowg < HH);
    float acc[4][8];
#pragma unroll
    for (int i = 0; i < 4; ++i)
#pragma unroll
        for (int j = 0; j < 8; ++j) acc[i][j] = 0.0f;
    for (int c = 0; c < CC; ++c) {
        float vv = 0.0f;
        if (rv) vv = x[(((size_t)b * CC + c) * HH + rowg) * WW + colc];
        xr[rr][colc] = vv;
        __syncthreads();
        for (int it = tid; it < 9 * OWW; it += 256) {
            int k = it >> 5; int q = it & 31;
            int kh = k / 3;  int kw = k - kh * 3;
            float wpos = (float)q * sw - 1.0f + (float)kw;
            float wbf = floorf(wpos);
            float fw = wpos - wbf;
            int wb = (int)wbf;
            float x00 = 0, x01 = 0, x10 = 0, x11 = 0;
            if (wb >= 0 && wb < WW)         { x00 = xr[kh][wb];     x10 = xr[kh + 1][wb]; }
            if (wb + 1 >= 0 && wb + 1 < WW) { x01 = xr[kh][wb + 1]; x11 = xr[kh + 1][wb + 1]; }
            float top = x00 * (1.0f - fw) + x01 * fw;
            float bot = x10 * (1.0f - fw) + x11 * fw;
            patch[k][q] = top * (1.0f - fh) + bot * fh;
        }
        __syncthreads();
        const float4* pv = (const float4*)&patch[0][0];
#pragma unroll
        for (int k = 0; k < 9; ++k) {
            const float* wb_ = w + (size_t)o0 * (CC * 9) + c * 9 + k;
            float wvv[4] = {wb_[0], wb_[1 * CC * 9], wb_[2 * CC * 9], wb_[3 * CC * 9]};
            float4 pa = pv[k * 8 + (q0 >> 2)];
            float4 pb = pv[k * 8 + (q0 >> 2) + 1];
#pragma unroll
            for (int oo2 = 0; oo2 < 4; ++oo2) {
                acc[oo2][0] += wvv[oo2] * pa.x; acc[oo2][1] += wvv[oo2] * pa.y;
                acc[oo2][2] += wvv[oo2] * pa.z; acc[oo2][3] += wvv[oo2] * pa.w;
                acc[oo2][4] += wvv[oo2] * pb.x; acc[oo2][5] += wvv[oo2] * pb.y;
                acc[oo2][6] += wvv[oo2] * pb.z; acc[oo2][7] += wvv[oo2] * pb.w;
            }
        }
    }
    float4 bv = ((const float4*)bias)[og];
    float bvv[4] = {bv.x, bv.y, bv.z, bv.w};
#pragma unroll
    for (int oo2 = 0; oo2 < 4; ++oo2) {
        size_t off = (((size_t)b * OO + o0 + oo2) * OHH + p) * OWW + q0;
        float4 r0, r1;
        r0.x = acc[oo2][0] + bvv[oo2]; r0.y = acc[oo2][1] + bvv[oo2];
        r0.z = acc[oo2][2] + bvv[oo2]; r0.w = acc[oo2][3] + bvv[oo2];
        r1.x = acc[oo2][4] + bvv[oo2]; r1.y = acc[oo2][5] + bvv[oo2];
        r1.z = acc[oo2][6] + bvv[oo2]; r1.w = acc[oo2][7] + bvv[oo2];
        *(float4*)(out + off)     = r0;
        *(float4*)(out + off + 4) = r1;
    }
}

extern "C" void kernel_launch(void* const* d_in, const int* in_sizes, int n_in,
                              void* d_out, int out_size, void* d_ws, size_t ws_size,
                              hipStream_t stream) {
    const float* x    = (const float*)d_in[0];
    const float* w    = (const float*)d_in[1];
    const float* bias = (const float*)d_in[2];
    const float* shp  = (const float*)d_in[3];
    const float* swp  = (const float*)d_in[4];
    float* out = (float*)d_out;

    const size_t wt_bytes = (size_t)OO * 9 * CC * sizeof(__bf16);   // 576 KB
    dim3 grid(BB, OHH);
    if (ws_size >= wt_bytes) {
        __bf16* wtp = (__bf16*)d_ws;
        int n = OO * 9 * CC;
        wtrans_bf16_kernel<<<(n + 255) / 256, 256, 0, stream>>>(w, wtp);
        conv_mfma_kernel<<<grid, 512, 0, stream>>>(x, wtp, bias, shp, swp, out);
    } else {
        conv_fallback_kernel<<<grid, 256, 0, stream>>>(x, w, bias, shp, swp, out);
    }
}